// Round 6
// baseline (86.565 us; speedup 1.0000x reference)
//
#include <hip/hip_runtime.h>

#define LOG2E 1.4426950408889634f
#define SCALE (2.0f * LOG2E)

__device__ __forceinline__ float fast_exp2(float x) { return __builtin_amdgcn_exp2f(x); }
__device__ __forceinline__ float fast_rcp(float x)  { return __builtin_amdgcn_rcpf(x); }

typedef __attribute__((ext_vector_type(8))) short bf16x8;
typedef __attribute__((ext_vector_type(4))) float f32x4;
typedef __attribute__((ext_vector_type(2))) float f32x2;
#define F2(u,v) ((f32x2){(u),(v)})

// ---------------- stage 0: pack A/B into bf16 hi/lo MFMA fragment panels ----------------
// Logical GEMM: C[m,n] = sum_{kp=0}^{1535} A[m,kp]*B[n,kp]
//   kp segment 0: x_hi*w_hi ; 1: x_lo*w_hi ; 2: x_hi*w_lo   (lo*lo dropped, ~1e-5 rel)
__global__ __launch_bounds__(256) void pack_kernel(const float* __restrict__ inputs,
                                                   const float* __restrict__ attn_W,
                                                   ushort* __restrict__ Ap,
                                                   ushort* __restrict__ Bp) {
    int tid = blockIdx.x * 256 + threadIdx.x;
    const bool isA = tid < 393216;
    int f = isA ? tid : tid - 393216;
    int l  = f & 63;
    int fr = (f >> 6) & 3;
    int ks = (f >> 8) & 1;
    int rem = f >> 9;
    int kt = rem % 24, tb = rem / 24;
    int kp = kt * 64 + ks * 32 + (l >> 4) * 8;
    int seg = kp >> 9, k = kp & 511;
    const float* src;
    bool useLo;
    if (isA) {
        int m = tb * 64 + fr * 16 + (l & 15);
        src = inputs + ((m & 255) * 8 + (m >> 8)) * 512 + k;
        useLo = (seg == 1);
    } else {
        int n = tb * 64 + fr * 16 + (l & 15);
        src = attn_W + (n & 511) * 1024 + (n >> 9) * 512 + k;
        useLo = (seg == 2);
    }
    float4 v0 = *(const float4*)src;
    float4 v1 = *(const float4*)(src + 4);
    float vv[8] = {v0.x, v0.y, v0.z, v0.w, v1.x, v1.y, v1.z, v1.w};
    ushort o[8];
#pragma unroll
    for (int j = 0; j < 8; ++j) {
        unsigned u = __float_as_uint(vv[j]);
        unsigned hi = (u + 0x7FFF + ((u >> 16) & 1)) >> 16;   // RN bf16
        if (useLo) {
            float lo = vv[j] - __uint_as_float(hi << 16);
            unsigned ul = __float_as_uint(lo);
            o[j] = (ushort)((ul + 0x7FFF + ((ul >> 16) & 1)) >> 16);
        } else {
            o[j] = (ushort)hi;
        }
    }
    ushort* dst = (isA ? Ap : Bp) + (long)f * 8;
    *(uint4*)dst = *(const uint4*)o;
}

// ---------------- stage 1: MFMA GEMM, tile 128x64, 4 waves 2x2, BK=64 dbuf ----------------
__global__ __launch_bounds__(256) void mfma_gemm(const ushort* __restrict__ Ap,
                                                 const ushort* __restrict__ Bp,
                                                 const float* __restrict__ attn_b,
                                                 float* __restrict__ E1,
                                                 float* __restrict__ E2) {
    const int mb = blockIdx.x & 15;
    const int nb = blockIdx.x >> 4;
    __shared__ ushort lds[2][12288];

    const int t = threadIdx.x;
    const int lane = t & 63, w = t >> 6;
    const int wr = w >> 1, wc = w & 1;

    const ushort* A0 = Ap + (long)(mb * 2 + 0) * 24 * 4096;
    const ushort* A1 = Ap + (long)(mb * 2 + 1) * 24 * 4096;
    const ushort* B0 = Bp + (long)nb * 24 * 4096;

    f32x4 acc[4][2];
#pragma unroll
    for (int i = 0; i < 4; ++i)
#pragma unroll
        for (int j = 0; j < 2; ++j)
            acc[i][j] = (f32x4){0.f, 0.f, 0.f, 0.f};

    uint4 st[6];
    st[0] = ((const uint4*)A0)[t];       st[1] = ((const uint4*)A0)[t + 256];
    st[2] = ((const uint4*)A1)[t];       st[3] = ((const uint4*)A1)[t + 256];
    st[4] = ((const uint4*)B0)[t];       st[5] = ((const uint4*)B0)[t + 256];
#pragma unroll
    for (int r = 0; r < 6; ++r) ((uint4*)lds[0])[t + r * 256] = st[r];
    __syncthreads();

    for (int kt = 0; kt < 24; ++kt) {
        if (kt < 23) {
            const uint4* a0 = (const uint4*)(A0 + (kt + 1) * 4096);
            const uint4* a1 = (const uint4*)(A1 + (kt + 1) * 4096);
            const uint4* b0 = (const uint4*)(B0 + (kt + 1) * 4096);
            st[0] = a0[t]; st[1] = a0[t + 256];
            st[2] = a1[t]; st[3] = a1[t + 256];
            st[4] = b0[t]; st[5] = b0[t + 256];
        }
        const ushort* buf = lds[kt & 1];
#pragma unroll
        for (int ks = 0; ks < 2; ++ks) {
            bf16x8 a[4], b[2];
#pragma unroll
            for (int mf = 0; mf < 4; ++mf)
                a[mf] = *(const bf16x8*)&buf[wr * 4096 + ks * 2048 + mf * 512 + lane * 8];
#pragma unroll
            for (int nn = 0; nn < 2; ++nn)
                b[nn] = *(const bf16x8*)&buf[8192 + ks * 2048 + (wc * 2 + nn) * 512 + lane * 8];
#pragma unroll
            for (int mf = 0; mf < 4; ++mf)
#pragma unroll
                for (int nn = 0; nn < 2; ++nn)
                    acc[mf][nn] = __builtin_amdgcn_mfma_f32_16x16x32_bf16(
                        a[mf], b[nn], acc[mf][nn], 0, 0, 0);
        }
        if (kt < 23) {
            ushort* nbuf = lds[(kt + 1) & 1];
#pragma unroll
            for (int r = 0; r < 6; ++r) ((uint4*)nbuf)[t + r * 256] = st[r];
            __syncthreads();
        }
    }

    const bool isE1 = (nb < 8);
    float* dst = isE1 ? E1 : E2;
    const int b = mb >> 1;
#pragma unroll
    for (int nn = 0; nn < 2; ++nn) {
        int n = nb * 64 + wc * 32 + nn * 16 + (lane & 15);
        int o = n & 511;
        float bias = isE1 ? attn_b[o] : 0.0f;
#pragma unroll
        for (int mf = 0; mf < 4; ++mf) {
            int ti = (mb & 1) * 4 + wr * 2 + (mf >> 1);
            int iibase = (mf & 1) * 16 + (lane >> 4) * 4;
            long rowoff = ((long)(b * 8 + ti) * 512 + o) * 32 + iibase;
#pragma unroll
            for (int r = 0; r < 4; ++r)
                dst[rowoff + r] = fast_exp2(SCALE * (acc[mf][nn][r] + bias));
        }
    }
}

// ---------------- stage 2: partial energies, 64x64 tile, 4x4/thread, 4-way rcp combine ----
// EP[s][b][i][j] = sum_{o in chunk s (64)} c_o * rcp(1 + E1[b,i,o]*E2[b,j,o])
// 4-way exact combine: sum_{q=0..3} c_q/y_q = n/d, y=1+x, d=y0y1y2y3,
//   n = (c0y1+c1y0)*y2y3 + (c2y3+c3y2)*y0y1
__global__ __launch_bounds__(256) void energy_kernel(const float* __restrict__ E1,
                                                     const float* __restrict__ E2,
                                                     const float* __restrict__ sW,
                                                     float* __restrict__ EP) {
    const int bid = blockIdx.x;          // 1024 = s(8) b(8) ti(4) tj(4)
    const int tj = bid & 3;
    const int ti = (bid >> 2) & 3;
    const int b  = (bid >> 4) & 7;
    const int s  = bid >> 7;
    __shared__ float As[64 * 33];        // [ii][oo] padded (+1 per 32)
    __shared__ float Bs[64 * 33];
    __shared__ float csh[64];

    const int t = threadIdx.x;
    const int tx = t & 15, ty = t >> 4;
    if (t < 64) csh[t] = 2.0f * sW[s * 64 + t];

    const int oo = t & 31, iig = t >> 5;   // staging roles
    const float* a_src = E1 + (long)(b * 8 + ti * 2 + (iig >> 2)) * 16384 + (iig & 3) * 8;
    const float* b_src = E2 + (long)(b * 8 + tj * 2 + (iig >> 2)) * 16384 + (iig & 3) * 8;

    f32x2 acc[4][2];
#pragma unroll
    for (int r = 0; r < 4; ++r)
#pragma unroll
        for (int cp = 0; cp < 2; ++cp) acc[r][cp] = F2(0.f, 0.f);

    const f32x2 one = F2(1.f, 1.f);

    for (int st = 0; st < 2; ++st) {
        const long ob = (long)(s * 64 + st * 32 + oo) * 32;
        float4 va0 = *(const float4*)(a_src + ob);
        float4 va1 = *(const float4*)(a_src + ob + 4);
        float4 vb0 = *(const float4*)(b_src + ob);
        float4 vb1 = *(const float4*)(b_src + ob + 4);
        __syncthreads();
        const int di = iig * 8;
        As[(di + 0) * 33 + oo] = va0.x; As[(di + 1) * 33 + oo] = va0.y;
        As[(di + 2) * 33 + oo] = va0.z; As[(di + 3) * 33 + oo] = va0.w;
        As[(di + 4) * 33 + oo] = va1.x; As[(di + 5) * 33 + oo] = va1.y;
        As[(di + 6) * 33 + oo] = va1.z; As[(di + 7) * 33 + oo] = va1.w;
        Bs[(di + 0) * 33 + oo] = vb0.x; Bs[(di + 1) * 33 + oo] = vb0.y;
        Bs[(di + 2) * 33 + oo] = vb0.z; Bs[(di + 3) * 33 + oo] = vb0.w;
        Bs[(di + 4) * 33 + oo] = vb1.x; Bs[(di + 5) * 33 + oo] = vb1.y;
        Bs[(di + 6) * 33 + oo] = vb1.z; Bs[(di + 7) * 33 + oo] = vb1.w;
        __syncthreads();

#pragma unroll
        for (int g = 0; g < 8; ++g) {
            float4 c4 = *(const float4*)&csh[st * 32 + g * 4];
            float4 av[4], bv[4];
#pragma unroll
            for (int r = 0; r < 4; ++r)
                av[r] = *(const float4*)&As[(ty * 4 + r) * 33 + g * 4];
#pragma unroll
            for (int c = 0; c < 4; ++c)
                bv[c] = *(const float4*)&Bs[(tx * 4 + c) * 33 + g * 4];
#pragma unroll
            for (int r = 0; r < 4; ++r) {
#pragma unroll
                for (int cp = 0; cp < 2; ++cp) {
                    const float4 B0 = bv[cp * 2], B1 = bv[cp * 2 + 1];
                    f32x2 y0 = F2(B0.x, B1.x) * av[r].x + one;
                    f32x2 y1 = F2(B0.y, B1.y) * av[r].y + one;
                    f32x2 y2 = F2(B0.z, B1.z) * av[r].z + one;
                    f32x2 y3 = F2(B0.w, B1.w) * av[r].w + one;
                    f32x2 y01 = y0 * y1, y23 = y2 * y3;
                    f32x2 d = y01 * y23;
                    f32x2 n01 = y1 * c4.x + y0 * c4.y;
                    f32x2 n23 = y3 * c4.z + y2 * c4.w;
                    f32x2 n = n01 * y23 + n23 * y01;
                    f32x2 rr = F2(fast_rcp(d.x), fast_rcp(d.y));
                    acc[r][cp] += n * rr;
                }
            }
        }
    }

    float* Eb = EP + (long)s * 524288 + (long)b * 65536 + (long)(ti * 64) * 256 + tj * 64;
#pragma unroll
    for (int r = 0; r < 4; ++r)
#pragma unroll
        for (int cp = 0; cp < 2; ++cp)
            *(f32x2*)&Eb[(ty * 4 + r) * 256 + tx * 4 + cp * 2] = acc[r][cp];
}

// ---------------- stage 3: combine 8 partials + softmax over i (axis=1) ----------------
__global__ __launch_bounds__(256) void softmax_kernel(const float* __restrict__ EP,
                                                      float* __restrict__ out) {
    const int b  = blockIdx.x >> 4;
    const int jt = blockIdx.x & 15;
    const int t  = threadIdx.x;
    const int jx = t & 15;
    const int iy = t >> 4;
    const long base = (long)b * 65536 + jt * 16 + jx;

    float v[16];
#pragma unroll
    for (int k = 0; k < 16; ++k) {
        long idx = base + (long)(iy + k * 16) * 256;
        float sum = 0.f;
#pragma unroll
        for (int p = 0; p < 8; ++p) sum += EP[(long)p * 524288 + idx];
        v[k] = -sum;
    }

    float m = v[0];
#pragma unroll
    for (int k = 1; k < 16; ++k) m = fmaxf(m, v[k]);

    __shared__ float red[256];
    red[t] = m;
    __syncthreads();
    if (t < 128) red[t] = fmaxf(red[t], red[t + 128]);
    __syncthreads();
    if (t < 64) red[t] = fmaxf(red[t], red[t + 64]);
    __syncthreads();
    if (t < 32) red[t] = fmaxf(red[t], red[t + 32]);
    __syncthreads();
    if (t < 16) red[t] = fmaxf(red[t], red[t + 16]);
    __syncthreads();
    m = red[jx];
    __syncthreads();

    float ssum = 0.f;
#pragma unroll
    for (int k = 0; k < 16; ++k) {
        v[k] = fast_exp2((v[k] - m) * LOG2E);
        ssum += v[k];
    }
    red[t] = ssum;
    __syncthreads();
    if (t < 128) red[t] += red[t + 128];
    __syncthreads();
    if (t < 64) red[t] += red[t + 64];
    __syncthreads();
    if (t < 32) red[t] += red[t + 32];
    __syncthreads();
    if (t < 16) red[t] += red[t + 16];
    __syncthreads();
    float inv = fast_rcp(red[jx]);

#pragma unroll
    for (int k = 0; k < 16; ++k) {
        long idx = base + (long)(iy + k * 16) * 256;
        out[idx] = v[k] * inv;
    }
}

extern "C" void kernel_launch(void* const* d_in, const int* in_sizes, int n_in,
                              void* d_out, int out_size, void* d_ws, size_t ws_size,
                              hipStream_t stream) {
    const float* inputs  = (const float*)d_in[0];  // (256, 8, 512)
    const float* attn_W  = (const float*)d_in[1];  // (512, 1024)
    const float* attn_b  = (const float*)d_in[2];  // (512,)
    const float* score_W = (const float*)d_in[3];  // (1, 512)
    float* out = (float*)d_out;                    // (8, 256, 256)

    float* ws = (float*)d_ws;
    float* E1 = ws;                                // 1M f32 exp panel
    float* E2 = ws + (1 << 20);                    // 1M f32
    float* EP = ws + (2 << 20);                    // 8 * 512K f32 partials (16 MB)
    ushort* Ap = (ushort*)(ws + (6 << 20));        // 3.146M bf16
    ushort* Bp = Ap + 3145728;                     // 1.573M bf16

    pack_kernel<<<2304, 256, 0, stream>>>(inputs, attn_W, Ap, Bp);
    mfma_gemm<<<256, 256, 0, stream>>>(Ap, Bp, attn_b, E1, E2);
    energy_kernel<<<1024, 256, 0, stream>>>(E1, E2, score_W, EP);
    softmax_kernel<<<128, 256, 0, stream>>>(EP, out);
}